// Round 4
// baseline (308.593 us; speedup 1.0000x reference)
//
#include <hip/hip_runtime.h>
#include <math.h>

#define T_TOKENS 4096
#define HIDDEN   2048
#define N_EXPERTS 8

// ---------------------------------------------------------------------------
// Kernel 1: fill router_indices [E*T, H] with value = (row % T), as float.
// Memset-shaped: block b owns rows [4b, 4b+4) = 32 KB CONTIGUOUS. Each
// thread issues 8 independent dwordx4 stores at constant offsets (value is
// constant within a row), mirroring __amd_rocclr_fillBufferAligned, which
// sustains 6.33 TB/s on this same buffer (R3 profile). The previous
// grid-stride version (8 stores 32 MB apart, address dep-chain per iter)
// ran ~5x slower than the memset.
// ---------------------------------------------------------------------------
__global__ __launch_bounds__(256) void fill_indices_kernel(float* __restrict__ out1)
{
    const int b   = blockIdx.x;    // 0..8191, row group = 4 rows of 2048 floats
    const int tid = threadIdx.x;   // 0..255
    float4* base = (float4*)out1 + (size_t)b * 2048;  // 4 rows x 512 float4
    #pragma unroll
    for (int r = 0; r < 4; r++) {
        float v = (float)((b * 4 + r) & (T_TOKENS - 1));
        float4 x = make_float4(v, v, v, v);
        base[r * 512 + tid]       = x;   // first half of row
        base[r * 512 + 256 + tid] = x;   // second half of row
    }
}

// ---------------------------------------------------------------------------
// Kernel 2: router logits + top-2 + sigmoid scatter. One wave per token,
// W (64 KB) staged in LDS, float4 dot products, 64-lane shuffle reduce,
// lane 0 does top-2 + sigmoid and writes the dense [E,T] column to both
// router_scores (out0) and router_probs (out2).
// ---------------------------------------------------------------------------
__global__ __launch_bounds__(256) void router_scores_kernel(
    const float* __restrict__ h, const float* __restrict__ w,
    float* __restrict__ out0, float* __restrict__ out2)
{
    __shared__ float wlds[N_EXPERTS * HIDDEN];  // 64 KB
    const float4* w4  = (const float4*)w;
    float4*       wl4 = (float4*)wlds;
    for (int i = threadIdx.x; i < (N_EXPERTS * HIDDEN) / 4; i += 256)
        wl4[i] = w4[i];
    __syncthreads();

    const int wave = threadIdx.x >> 6;
    const int lane = threadIdx.x & 63;
    const int t = blockIdx.x * 4 + wave;  // grid = 1024 blocks -> t in [0,4096)

    const float4* h4 = (const float4*)(h + (size_t)t * HIDDEN);
    float acc[N_EXPERTS];
    #pragma unroll
    for (int e = 0; e < N_EXPERTS; e++) acc[e] = 0.f;

    #pragma unroll
    for (int k = 0; k < 8; k++) {
        float4 hv = h4[k * 64 + lane];
        #pragma unroll
        for (int e = 0; e < N_EXPERTS; e++) {
            float4 wv = wl4[e * 512 + k * 64 + lane];
            acc[e] += hv.x * wv.x + hv.y * wv.y + hv.z * wv.z + hv.w * wv.w;
        }
    }

    #pragma unroll
    for (int e = 0; e < N_EXPERTS; e++) {
        #pragma unroll
        for (int off = 32; off > 0; off >>= 1)
            acc[e] += __shfl_down(acc[e], off, 64);
    }

    if (lane == 0) {
        int i1 = 0; float v1 = acc[0];
        #pragma unroll
        for (int e = 1; e < N_EXPERTS; e++)
            if (acc[e] > v1) { v1 = acc[e]; i1 = e; }
        int i2 = -1; float v2 = -INFINITY;
        #pragma unroll
        for (int e = 0; e < N_EXPERTS; e++)
            if (e != i1 && acc[e] > v2) { v2 = acc[e]; i2 = e; }

        float s1 = 1.f / (1.f + expf(-v1));
        float s2 = 1.f / (1.f + expf(-v2));

        #pragma unroll
        for (int e = 0; e < N_EXPERTS; e++) {
            float val = (e == i1) ? s1 : ((e == i2) ? s2 : 0.f);
            out0[e * T_TOKENS + t] = val;
            out2[e * T_TOKENS + t] = val;
        }
    }
}

extern "C" void kernel_launch(void* const* d_in, const int* in_sizes, int n_in,
                              void* d_out, int out_size, void* d_ws, size_t ws_size,
                              hipStream_t stream) {
    const float* h = (const float*)d_in[0];   // [4096, 2048] f32
    const float* w = (const float*)d_in[1];   // [8, 2048] f32
    // d_in[2] = top_k (always 2)

    float* out  = (float*)d_out;
    float* out0 = out;                                   // router_scores [8,4096]
    float* out1 = out + N_EXPERTS * T_TOKENS;            // router_indices [32768,2048]
    float* out2 = out1 + (size_t)N_EXPERTS * T_TOKENS * HIDDEN;  // router_probs [32768,1]

    hipLaunchKernelGGL(fill_indices_kernel, dim3(8192), dim3(256), 0, stream, out1);
    hipLaunchKernelGGL(router_scores_kernel, dim3(1024), dim3(256), 0, stream,
                       h, w, out0, out2);
}

// Round 5
// 299.655 us; speedup vs baseline: 1.0298x; 1.0298x over previous
//
#include <hip/hip_runtime.h>
#include <math.h>

#define T_TOKENS 4096
#define HIDDEN   2048
#define N_EXPERTS 8

// ---------------------------------------------------------------------------
// Fused kernel: 8192 blocks x 256 threads.
//   * Every block fills its contiguous 32 KB chunk of router_indices
//     (rows 4b..4b+3, value = row id broadcast over H).
//   * Blocks 0..1023 additionally compute the router for tokens 4b..4b+3
//     (one wave per token): logits via float4 dots against W read straight
//     from global (64 KB, L2-hot), 64-lane shuffle reduce, top-2 + sigmoid,
//     dense [E,T] column written to router_scores and router_probs.
// R2-R4 showed the fill pattern is NOT the bottleneck (three patterns, same
// 297-310 us): dur_us is dominated by the harness's 1.075 GB ws poison
// (~170 us) + 268 MB out poison (~45 us) + restores. Fusing removes the one
// remaining launch gap and overlaps router reads with fill writes.
// ---------------------------------------------------------------------------
__global__ __launch_bounds__(256) void router_fused_kernel(
    const float* __restrict__ h, const float* __restrict__ w,
    float* __restrict__ out0, float* __restrict__ out1, float* __restrict__ out2)
{
    const int b   = blockIdx.x;    // 0..8191
    const int tid = threadIdx.x;   // 0..255

    // ---- router phase (blocks 0..1023 only; wave-uniform branch) ----
    if (b < T_TOKENS / 4) {
        const int wave = tid >> 6;
        const int lane = tid & 63;
        const int t = b * 4 + wave;

        const float4* h4 = (const float4*)h + (size_t)t * (HIDDEN / 4);
        const float4* w4 = (const float4*)w;

        float acc[N_EXPERTS];
        #pragma unroll
        for (int e = 0; e < N_EXPERTS; e++) acc[e] = 0.f;

        #pragma unroll
        for (int k = 0; k < 8; k++) {
            float4 hv = h4[k * 64 + lane];
            #pragma unroll
            for (int e = 0; e < N_EXPERTS; e++) {
                float4 wv = w4[e * (HIDDEN / 4) + k * 64 + lane];
                acc[e] += hv.x * wv.x + hv.y * wv.y + hv.z * wv.z + hv.w * wv.w;
            }
        }

        #pragma unroll
        for (int e = 0; e < N_EXPERTS; e++) {
            #pragma unroll
            for (int off = 32; off > 0; off >>= 1)
                acc[e] += __shfl_down(acc[e], off, 64);
        }

        if (lane == 0) {
            int i1 = 0; float v1 = acc[0];
            #pragma unroll
            for (int e = 1; e < N_EXPERTS; e++)
                if (acc[e] > v1) { v1 = acc[e]; i1 = e; }
            int i2 = -1; float v2 = -INFINITY;
            #pragma unroll
            for (int e = 0; e < N_EXPERTS; e++)
                if (e != i1 && acc[e] > v2) { v2 = acc[e]; i2 = e; }

            float s1 = 1.f / (1.f + expf(-v1));
            float s2 = 1.f / (1.f + expf(-v2));

            #pragma unroll
            for (int e = 0; e < N_EXPERTS; e++) {
                float val = (e == i1) ? s1 : ((e == i2) ? s2 : 0.f);
                out0[e * T_TOKENS + t] = val;
                out2[e * T_TOKENS + t] = val;
            }
        }
    }

    // ---- fill phase (all blocks): rows 4b..4b+3 of router_indices ----
    float4* base = (float4*)out1 + (size_t)b * 2048;  // 4 rows x 512 float4
    #pragma unroll
    for (int r = 0; r < 4; r++) {
        float v = (float)((b * 4 + r) & (T_TOKENS - 1));
        float4 x = make_float4(v, v, v, v);
        base[r * 512 + tid]       = x;
        base[r * 512 + 256 + tid] = x;
    }
}

extern "C" void kernel_launch(void* const* d_in, const int* in_sizes, int n_in,
                              void* d_out, int out_size, void* d_ws, size_t ws_size,
                              hipStream_t stream) {
    const float* h = (const float*)d_in[0];   // [4096, 2048] f32
    const float* w = (const float*)d_in[1];   // [8, 2048] f32
    // d_in[2] = top_k (always 2)

    float* out  = (float*)d_out;
    float* out0 = out;                                   // router_scores [8,4096]
    float* out1 = out + N_EXPERTS * T_TOKENS;            // router_indices [32768,2048]
    float* out2 = out1 + (size_t)N_EXPERTS * T_TOKENS * HIDDEN;  // router_probs [32768,1]

    hipLaunchKernelGGL(router_fused_kernel, dim3(8192), dim3(256), 0, stream,
                       h, w, out0, out1, out2);
}